// Round 1
// baseline (3004.921 us; speedup 1.0000x reference)
//
#include <hip/hip_runtime.h>
#include <math.h>

// Shapes (fixed by the problem): B=32, S=1024, C=640, H=8, D=80, frames=16, videos=2
#define C_DIM 640
#define S_DIM 1024
#define H_NUM 8
#define D_DIM 80
#define FRAMES 16

// ---------------------------------------------------------------------------
// Generic fp32 GEMM:  out[g*out_gs + rr*out_rs + col] =
//     sum_k A[g*a_gs + rr*C + k] * W[k*C + col] (+ bias[col]) (+ residual[row*C+col])
// where row = m0.., g = row>>rpg_shift, rr = row & ((1<<rpg_shift)-1).
// Tile 64x64, BK=16, 256 threads, 4x4 micro-tile. M,N,K all divide evenly here.
// ---------------------------------------------------------------------------
__global__ __launch_bounds__(256)
void gemm_kernel(const float* __restrict__ A, const float* __restrict__ W,
                 const float* __restrict__ bias, const float* __restrict__ residual,
                 float* __restrict__ out,
                 int nTilesN, int rpg_shift, long long a_gs,
                 long long out_gs, int out_rs)
{
    __shared__ float As[16 * 68];   // [k][m], pitch 68 (16B-aligned, conflict-safe)
    __shared__ float Bs[16 * 64];   // [k][n]

    const int tid = threadIdx.x;
    const int bid = blockIdx.x;
    const int bm = bid / nTilesN, bn = bid % nTilesN;
    const int m0 = bm * 64, n0 = bn * 64;
    const int r2 = tid >> 4, c2 = tid & 15;

    // staging assignments
    const int sm  = tid >> 2;            // 0..63 : A-tile row
    const int sk4 = (tid & 3) << 2;      // 0,4,8,12 : A-tile k (float4)
    const int wk  = tid >> 4;            // 0..15 : W-tile k row
    const int wn4 = (tid & 15) << 2;     // 0..60 : W-tile col (float4)

    const int rowA = m0 + sm;
    const int gA   = rowA >> rpg_shift;
    const int rrA  = rowA & ((1 << rpg_shift) - 1);
    const float* aRow = A + (long long)gA * a_gs + (long long)rrA * C_DIM;
    const float* wPtr = W + (long long)wk * C_DIM + n0 + wn4;

    float acc[4][4] = {};

    for (int k0 = 0; k0 < C_DIM; k0 += 16) {
        __syncthreads();
        float4 av = *(const float4*)(aRow + k0 + sk4);
        As[(sk4 + 0) * 68 + sm] = av.x;
        As[(sk4 + 1) * 68 + sm] = av.y;
        As[(sk4 + 2) * 68 + sm] = av.z;
        As[(sk4 + 3) * 68 + sm] = av.w;
        float4 wv = *(const float4*)(wPtr + (long long)k0 * C_DIM);
        *(float4*)(&Bs[wk * 64 + wn4]) = wv;
        __syncthreads();
        #pragma unroll
        for (int k = 0; k < 16; ++k) {
            float4 a4 = *(const float4*)(&As[k * 68 + (r2 << 2)]);
            float4 b4 = *(const float4*)(&Bs[k * 64 + (c2 << 2)]);
            float a[4] = {a4.x, a4.y, a4.z, a4.w};
            float b[4] = {b4.x, b4.y, b4.z, b4.w};
            #pragma unroll
            for (int i = 0; i < 4; ++i)
                #pragma unroll
                for (int j = 0; j < 4; ++j)
                    acc[i][j] = fmaf(a[i], b[j], acc[i][j]);
        }
    }

    const int col0 = n0 + (c2 << 2);
    float4 bv4 = {0.f, 0.f, 0.f, 0.f};
    if (bias) bv4 = *(const float4*)(bias + col0);
    #pragma unroll
    for (int i = 0; i < 4; ++i) {
        const int row = m0 + (r2 << 2) + i;
        const int g  = row >> rpg_shift;
        const int rr = row & ((1 << rpg_shift) - 1);
        float4 o4;
        o4.x = acc[i][0] + bv4.x;
        o4.y = acc[i][1] + bv4.y;
        o4.z = acc[i][2] + bv4.z;
        o4.w = acc[i][3] + bv4.w;
        if (residual) {
            float4 rr4 = *(const float4*)(residual + (long long)row * C_DIM + col0);
            o4.x += rr4.x; o4.y += rr4.y; o4.z += rr4.z; o4.w += rr4.w;
        }
        *(float4*)(out + (long long)g * out_gs + (long long)rr * out_rs + col0) = o4;
    }
}

// ---------------------------------------------------------------------------
// Flash attention (fp32). One block = (video v, frame f, head h, 64 query rows).
// Q-tile and K-tile staged in LDS transposed ([d][row], pitch 68) so the
// score phase does two ds_read_b128 per d per thread. Online softmax with
// running (m,l). PV reads V directly from global (20KB/tile -> L1/L2 hot).
// Thread map: r2=tid>>4 owns rows r2*4..r2*4+3 in BOTH phases;
//   scores: t2=tid&15 owns keys t2*4..+3 ; PV: d2=tid&15 owns dims d2*5..+4.
// ---------------------------------------------------------------------------
__global__ __launch_bounds__(256)
void attn_kernel(const float* __restrict__ Q, const float* __restrict__ Kb,
                 const float* __restrict__ Vb, float* __restrict__ O)
{
    __shared__ float Qt[80 * 68];   // [d][r]
    __shared__ float Kt[80 * 68];   // [d][t]
    __shared__ float St[64 * 68];   // [t][r]  scores then probs
    __shared__ float m_run[64], l_run[64], sf[64];
    __shared__ float pred[4 * 64];

    const int tid = threadIdx.x;
    const int bid = blockIdx.x;
    const int sb = bid & 15;
    const int f  = (bid >> 4) & 15;
    const int h  = (bid >> 8) & 7;
    const int v  = bid >> 11;
    const int s0 = sb << 6;

    const float scale = 0.11180339887498948f;   // 1/sqrt(80)

    const long long qbase =
        ((long long)((v * FRAMES + f) * S_DIM + s0)) * C_DIM + h * D_DIM;
    for (int e = tid; e < 64 * 80; e += 256) {
        int r = e / 80, d = e - r * 80;
        Qt[d * 68 + r] = Q[qbase + (long long)r * C_DIM + d] * scale;
    }
    if (tid < 64) { m_run[tid] = -INFINITY; l_run[tid] = 0.f; }

    const int r2 = tid >> 4;          // row group (both phases)
    const int t2 = tid & 15;          // key group (scores)
    const int d2 = tid & 15;          // dim group (PV)
    const int rsm = tid & 63, qd = tid >> 6;   // softmax map

    const long long kvbase = (long long)v * S_DIM * C_DIM + h * D_DIM;
    const float* Kp = Kb + kvbase;
    const float* Vp = Vb + kvbase;

    float acc[4][5] = {};

    for (int t0 = 0; t0 < S_DIM; t0 += 64) {
        __syncthreads();                       // Kt/St free to overwrite
        for (int e = tid; e < 64 * 80; e += 256) {
            int r = e / 80, d = e - r * 80;
            Kt[d * 68 + r] = Kp[(long long)(t0 + r) * C_DIM + d];
        }
        __syncthreads();

        // ---- scores: S = (Q*scale) . K^T ----
        float as[4][4] = {};
        #pragma unroll 4
        for (int d = 0; d < 80; ++d) {
            float4 q4 = *(const float4*)(&Qt[d * 68 + (r2 << 2)]);
            float4 k4 = *(const float4*)(&Kt[d * 68 + (t2 << 2)]);
            float qa[4] = {q4.x, q4.y, q4.z, q4.w};
            float kk[4] = {k4.x, k4.y, k4.z, k4.w};
            #pragma unroll
            for (int i = 0; i < 4; ++i)
                #pragma unroll
                for (int j = 0; j < 4; ++j)
                    as[i][j] = fmaf(qa[i], kk[j], as[i][j]);
        }
        #pragma unroll
        for (int j = 0; j < 4; ++j) {
            float4 w4 = {as[0][j], as[1][j], as[2][j], as[3][j]};
            *(float4*)(&St[(t2 * 4 + j) * 68 + (r2 << 2)]) = w4;
        }
        __syncthreads();

        // ---- online softmax ----
        {
            float pm = -INFINITY;
            #pragma unroll
            for (int t = 0; t < 16; ++t)
                pm = fmaxf(pm, St[(qd * 16 + t) * 68 + rsm]);
            pred[qd * 64 + rsm] = pm;
        }
        __syncthreads();
        if (tid < 64) {
            float mt = fmaxf(fmaxf(pred[tid], pred[64 + tid]),
                             fmaxf(pred[128 + tid], pred[192 + tid]));
            float mold = m_run[tid];
            float mnew = fmaxf(mold, mt);
            float s = __expf(mold - mnew);     // first tile: exp(-inf)=0
            sf[tid] = s;
            l_run[tid] *= s;
            m_run[tid] = mnew;
        }
        __syncthreads();
        {
            float mn = m_run[rsm];
            float ps = 0.f;
            #pragma unroll
            for (int t = 0; t < 16; ++t) {
                int idx = (qd * 16 + t) * 68 + rsm;
                float p = __expf(St[idx] - mn);
                St[idx] = p;
                ps += p;
            }
            pred[qd * 64 + rsm] = ps;
        }
        __syncthreads();
        if (tid < 64)
            l_run[tid] += pred[tid] + pred[64 + tid] + pred[128 + tid] + pred[192 + tid];

        // ---- PV: acc = acc*sf + P @ V ----
        float sfl[4];
        #pragma unroll
        for (int i = 0; i < 4; ++i) sfl[i] = sf[(r2 << 2) + i];
        #pragma unroll
        for (int i = 0; i < 4; ++i)
            #pragma unroll
            for (int jd = 0; jd < 5; ++jd) acc[i][jd] *= sfl[i];

        #pragma unroll 2
        for (int t = 0; t < 64; ++t) {
            float4 p4 = *(const float4*)(&St[t * 68 + (r2 << 2)]);
            float p[4] = {p4.x, p4.y, p4.z, p4.w};
            const float* vrow = Vp + (long long)(t0 + t) * C_DIM + d2 * 5;
            float vv[5];
            #pragma unroll
            for (int jd = 0; jd < 5; ++jd) vv[jd] = vrow[jd];
            #pragma unroll
            for (int i = 0; i < 4; ++i)
                #pragma unroll
                for (int jd = 0; jd < 5; ++jd)
                    acc[i][jd] = fmaf(p[i], vv[jd], acc[i][jd]);
        }
    }
    __syncthreads();   // last l_run update

    float inv[4];
    #pragma unroll
    for (int i = 0; i < 4; ++i) inv[i] = 1.0f / l_run[(r2 << 2) + i];
    #pragma unroll
    for (int i = 0; i < 4; ++i) {
        long long rbase = qbase + (long long)((r2 << 2) + i) * C_DIM + d2 * 5;
        #pragma unroll
        for (int jd = 0; jd < 5; ++jd)
            O[rbase + jd] = acc[i][jd] * inv[i];
    }
}

// ---------------------------------------------------------------------------
// Launch. Workspace layout (floats):
//   Qb : 32768*640  (83.9 MB)
//   Kb : 2048*640   ( 5.2 MB)   [v][t][C]
//   Vb : 2048*640   ( 5.2 MB)   [v][t][C]
//   Ob : 32768*640  (83.9 MB)
// total ~178.3 MB of d_ws.
// ---------------------------------------------------------------------------
extern "C" void kernel_launch(void* const* d_in, const int* in_sizes, int n_in,
                              void* d_out, int out_size, void* d_ws, size_t ws_size,
                              hipStream_t stream) {
    const float* hs = (const float*)d_in[0];
    const float* Wq = (const float*)d_in[1];
    const float* Wk = (const float*)d_in[2];
    const float* Wv = (const float*)d_in[3];
    const float* Wo = (const float*)d_in[4];
    const float* bq = (const float*)d_in[5];
    const float* bk = (const float*)d_in[6];
    const float* bv = (const float*)d_in[7];
    const float* bo = (const float*)d_in[8];
    float* out = (float*)d_out;

    float* ws = (float*)d_ws;
    float* Qb = ws;
    float* Kb = Qb + 32768LL * 640;
    float* Vb = Kb + 2048LL * 640;
    float* Ob = Vb + 2048LL * 640;

    dim3 blk(256);

    // Q = hs @ Wq + bq   -> Qb [32768,640]
    gemm_kernel<<<(32768 / 64) * 10, blk, 0, stream>>>(
        hs, Wq, bq, nullptr, Qb, 10, 30, 0LL, 0LL, C_DIM);

    // K = hs[v*16] @ Wk + bk -> Kb [v][1024][640]  (row gather: group=row>>10)
    gemm_kernel<<<(2048 / 64) * 10, blk, 0, stream>>>(
        hs, Wk, bk, nullptr, Kb, 10, 10,
        (long long)FRAMES * S_DIM * C_DIM, (long long)S_DIM * C_DIM, C_DIM);

    // V = hs[v*16] @ Wv + bv -> Vb
    gemm_kernel<<<(2048 / 64) * 10, blk, 0, stream>>>(
        hs, Wv, bv, nullptr, Vb, 10, 10,
        (long long)FRAMES * S_DIM * C_DIM, (long long)S_DIM * C_DIM, C_DIM);

    // attention -> Ob [32768,640]
    attn_kernel<<<2 * H_NUM * FRAMES * (S_DIM / 64), blk, 0, stream>>>(Qb, Kb, Vb, Ob);

    // out = Ob @ Wo + bo + hs
    gemm_kernel<<<(32768 / 64) * 10, blk, 0, stream>>>(
        Ob, Wo, bo, hs, out, 10, 30, 0LL, 0LL, C_DIM);
}

// Round 2
// 800.037 us; speedup vs baseline: 3.7560x; 3.7560x over previous
//
#include <hip/hip_runtime.h>
#include <math.h>

// B=32, S=1024, C=640, H=8, D=80, frames=16, videos=2
#define C_DIM 640
#define S_DIM 1024
#define H_NUM 8
#define D_DIM 80
#define FRAMES 16

typedef __attribute__((ext_vector_type(8))) short short8;   // 8 x bf16
typedef __attribute__((ext_vector_type(4))) float f32x4;
typedef unsigned short ushort_t;

__device__ __forceinline__ ushort_t f2bf(float x) {
    union { float f; unsigned u; } uf; uf.f = x;
    unsigned r = uf.u + 0x7fffu + ((uf.u >> 16) & 1u);   // RNE
    return (ushort_t)(r >> 16);
}

// ---------------------------------------------------------------------------
// fp32 -> bf16 elementwise (8 elems/thread)
// ---------------------------------------------------------------------------
__global__ __launch_bounds__(256)
void conv_bf16(const float* __restrict__ in, ushort_t* __restrict__ out, int n8) {
    int i = blockIdx.x * 256 + threadIdx.x;
    if (i >= n8) return;
    const float4* p = (const float4*)(in + (long long)i * 8);
    float4 a = p[0], b = p[1];
    short8 o;
    o[0] = (short)f2bf(a.x); o[1] = (short)f2bf(a.y);
    o[2] = (short)f2bf(a.z); o[3] = (short)f2bf(a.w);
    o[4] = (short)f2bf(b.x); o[5] = (short)f2bf(b.y);
    o[6] = (short)f2bf(b.z); o[7] = (short)f2bf(b.w);
    *(short8*)(out + (long long)i * 8) = o;
}

// ---------------------------------------------------------------------------
// W [640][640] fp32 -> Wt [640][640] bf16 transposed (Wt[n][k] = W[k][n])
// ---------------------------------------------------------------------------
__global__ __launch_bounds__(256)
void transpose_w(const float* __restrict__ W, ushort_t* __restrict__ T) {
    __shared__ float Ls[64][65];
    const int tid = threadIdx.x;
    const int r0 = blockIdx.y * 64, c0 = blockIdx.x * 64;
    for (int e = tid; e < 4096; e += 256) {
        int r = e >> 6, c = e & 63;
        Ls[c][r] = W[(long long)(r0 + r) * C_DIM + c0 + c];
    }
    __syncthreads();
    for (int e = tid; e < 4096; e += 256) {
        int cc = e >> 6, rr = e & 63;
        T[(long long)(c0 + cc) * C_DIM + r0 + rr] = f2bf(Ls[cc][rr]);
    }
}

// ---------------------------------------------------------------------------
// bf16 MFMA GEMM: out[row][col] = (sum_k A[row][k]*Wt[col][k] + bias[col])*out_scale
//                 (+ residual[row][col]); out is bf16 or fp32.
// Tile 128x128, BK=32, 256 thr / 4 waves; wave w: rows 32w..32w+31, all 128 cols.
// A-row gather: arow = (row>>rpg_shift)*a_gs + (row&mask)*C.  Output rows flat.
// LDS pitch 40 ushorts (80B): 16B aligned, 2-way-max bank pattern.
// ---------------------------------------------------------------------------
__global__ __launch_bounds__(256)
void gemm_bf16(const ushort_t* __restrict__ A, const ushort_t* __restrict__ Wt,
               const float* __restrict__ bias, const float* __restrict__ residual,
               void* __restrict__ outp, int out_bf16, float out_scale,
               int nTilesN, int rpg_shift, long long a_gs)
{
    __shared__ ushort_t As[128 * 40];
    __shared__ ushort_t Bs[128 * 40];

    const int tid = threadIdx.x, bid = blockIdx.x;
    const int bm = bid / nTilesN, bn = bid % nTilesN;
    const int m0 = bm * 128, n0 = bn * 128;
    const int w = tid >> 6, l = tid & 63, g = l >> 4, li = l & 15;

    const int r0c = tid >> 2, cc = (tid & 3) * 8;
    const int maskR = (1 << rpg_shift) - 1;
    const int rowA0 = m0 + r0c, rowA1 = rowA0 + 64;
    const ushort_t* aP0 = A + (long long)(rowA0 >> rpg_shift) * a_gs
                            + (long long)(rowA0 & maskR) * C_DIM + cc;
    const ushort_t* aP1 = A + (long long)(rowA1 >> rpg_shift) * a_gs
                            + (long long)(rowA1 & maskR) * C_DIM + cc;
    const ushort_t* bP0 = Wt + (long long)(n0 + r0c) * C_DIM + cc;
    const ushort_t* bP1 = bP0 + 64 * C_DIM;
    const int sIdx0 = r0c * 40 + cc, sIdx1 = sIdx0 + 64 * 40;

    f32x4 acc[2][8] = {};

    for (int k0 = 0; k0 < C_DIM; k0 += 32) {
        __syncthreads();
        *(short8*)&As[sIdx0] = *(const short8*)(aP0 + k0);
        *(short8*)&As[sIdx1] = *(const short8*)(aP1 + k0);
        *(short8*)&Bs[sIdx0] = *(const short8*)(bP0 + k0);
        *(short8*)&Bs[sIdx1] = *(const short8*)(bP1 + k0);
        __syncthreads();
        short8 av0 = *(const short8*)&As[(32 * w + li) * 40 + 8 * g];
        short8 av1 = *(const short8*)&As[(32 * w + 16 + li) * 40 + 8 * g];
        #pragma unroll
        for (int cf = 0; cf < 8; ++cf) {
            short8 bv = *(const short8*)&Bs[(16 * cf + li) * 40 + 8 * g];
            acc[0][cf] = __builtin_amdgcn_mfma_f32_16x16x32_bf16(av0, bv, acc[0][cf], 0, 0, 0);
            acc[1][cf] = __builtin_amdgcn_mfma_f32_16x16x32_bf16(av1, bv, acc[1][cf], 0, 0, 0);
        }
    }

    #pragma unroll
    for (int fr = 0; fr < 2; ++fr) {
        #pragma unroll
        for (int cf = 0; cf < 8; ++cf) {
            const int col = n0 + 16 * cf + li;
            const float bcol = bias[col];
            #pragma unroll
            for (int r = 0; r < 4; ++r) {
                const int row = m0 + 32 * w + 16 * fr + 4 * g + r;
                float vv = (acc[fr][cf][r] + bcol) * out_scale;
                if (residual) vv += residual[(long long)row * C_DIM + col];
                if (out_bf16) ((ushort_t*)outp)[(long long)row * C_DIM + col] = f2bf(vv);
                else          ((float*)outp)[(long long)row * C_DIM + col] = vv;
            }
        }
    }
}

// ---------------------------------------------------------------------------
// MFMA flash attention. Block = (v,f,h, 64 q-rows); 4 waves, wave w owns rows
// 16w..16w+15. QK^T: A=Q rows, B=K rows (contraction d, no transpose needed).
// D=80 -> k-steps {32,32,16}: remainder step zeroes fragments for g>=2.
// Softmax wave-parallel via shfl_xor over 16-lane col groups. P->LDS bf16
// (XOR swizzle, wave-private rows). V staged transposed+swizzled so PV
// B-frag is a contiguous ds_read_b128.
// ---------------------------------------------------------------------------
__global__ __launch_bounds__(256)
void attn_mfma(const ushort_t* __restrict__ Qb, const ushort_t* __restrict__ Kb,
               const ushort_t* __restrict__ Vb, ushort_t* __restrict__ Ob)
{
    __shared__ ushort_t Qs[64 * 88];   // [q][d], pitch 88
    __shared__ ushort_t Ks[64 * 88];   // [t][d]
    __shared__ ushort_t Vt[80 * 64];   // [d][t], idx ^ ((d&7)<<3)
    __shared__ ushort_t Ps[64 * 64];   // [q][t], idx ^ ((q&7)<<3)

    const int tid = threadIdx.x, bid = blockIdx.x;
    const int sb = bid & 15, f = (bid >> 4) & 15, h = (bid >> 8) & 7, v = bid >> 11;
    const int s0 = sb * 64;
    const int w = tid >> 6, l = tid & 63, g = l >> 4, li = l & 15;

    const ushort_t* Qg = Qb + (long long)((v * FRAMES + f) * S_DIM + s0) * C_DIM + h * D_DIM;
    const ushort_t* Kg = Kb + (long long)v * S_DIM * C_DIM + h * D_DIM;
    const ushort_t* Vg = Vb + (long long)v * S_DIM * C_DIM + h * D_DIM;

    for (int e = tid; e < 640; e += 256) {           // 64 rows x 10 chunks
        int t = e / 10, c = e - 10 * t;
        *(short8*)&Qs[t * 88 + c * 8] = *(const short8*)(Qg + t * C_DIM + c * 8);
    }

    float m_run[4], l_run[4];
    #pragma unroll
    for (int r = 0; r < 4; ++r) { m_run[r] = -1e30f; l_run[r] = 0.f; }
    f32x4 accv[5] = {};
    __syncthreads();

    for (int t0 = 0; t0 < S_DIM; t0 += 64) {
        for (int e = tid; e < 640; e += 256) {
            int t = e / 10, c = e - 10 * t;
            *(short8*)&Ks[t * 88 + c * 8] = *(const short8*)(Kg + (t0 + t) * C_DIM + c * 8);
            short8 v8 = *(const short8*)(Vg + (t0 + t) * C_DIM + c * 8);
            int d0 = c * 8;
            #pragma unroll
            for (int j = 0; j < 8; ++j)
                Vt[((d0 + j) * 64 + t) ^ (j << 3)] = (ushort_t)v8[j];
        }
        __syncthreads();

        // ---- scores: S[q][t], q = 16w+4g+r, t = 16tf+li ----
        f32x4 sc[4] = {};
        #pragma unroll
        for (int ks = 0; ks < 3; ++ks) {
            const bool valid = (ks < 2) || (g < 2);
            short8 aq = {};
            if (valid) aq = *(const short8*)&Qs[(16 * w + li) * 88 + ks * 32 + 8 * g];
            #pragma unroll
            for (int tf = 0; tf < 4; ++tf) {
                short8 bk = {};
                if (valid) bk = *(const short8*)&Ks[(16 * tf + li) * 88 + ks * 32 + 8 * g];
                sc[tf] = __builtin_amdgcn_mfma_f32_16x16x32_bf16(aq, bk, sc[tf], 0, 0, 0);
            }
        }

        // ---- online softmax (rows wave-local; reduce across 16-lane col group) ----
        float mt[4];
        #pragma unroll
        for (int r = 0; r < 4; ++r)
            mt[r] = fmaxf(fmaxf(sc[0][r], sc[1][r]), fmaxf(sc[2][r], sc[3][r]));
        #pragma unroll
        for (int mk = 1; mk < 16; mk <<= 1)
            #pragma unroll
            for (int r = 0; r < 4; ++r)
                mt[r] = fmaxf(mt[r], __shfl_xor(mt[r], mk, 64));
        float sca[4];
        #pragma unroll
        for (int r = 0; r < 4; ++r) {
            float mn = fmaxf(m_run[r], mt[r]);
            sca[r] = __expf(m_run[r] - mn);
            m_run[r] = mn;
        }
        float ps[4] = {0.f, 0.f, 0.f, 0.f};
        #pragma unroll
        for (int tf = 0; tf < 4; ++tf) {
            #pragma unroll
            for (int r = 0; r < 4; ++r) {
                float p = __expf(sc[tf][r] - m_run[r]);
                ps[r] += p;
                const int q = 16 * w + 4 * g + r;
                Ps[(q * 64 + 16 * tf + li) ^ (((4 * g + r) & 7) << 3)] = f2bf(p);
            }
        }
        #pragma unroll
        for (int mk = 1; mk < 16; mk <<= 1)
            #pragma unroll
            for (int r = 0; r < 4; ++r)
                ps[r] += __shfl_xor(ps[r], mk, 64);
        #pragma unroll
        for (int r = 0; r < 4; ++r) l_run[r] = l_run[r] * sca[r] + ps[r];
        #pragma unroll
        for (int df = 0; df < 5; ++df)
            #pragma unroll
            for (int r = 0; r < 4; ++r) accv[df][r] *= sca[r];

        __syncthreads();   // P visible (cross-lane), Vt stable

        // ---- PV: out[q][d] += P[q][t] V[t][d] ----
        #pragma unroll
        for (int ks = 0; ks < 2; ++ks) {
            short8 pa = *(const short8*)&Ps[((16 * w + li) * 64 + ks * 32 + 8 * g) ^ ((li & 7) << 3)];
            #pragma unroll
            for (int df = 0; df < 5; ++df) {
                short8 vb = *(const short8*)&Vt[((16 * df + li) * 64 + ks * 32 + 8 * g) ^ ((li & 7) << 3)];
                accv[df] = __builtin_amdgcn_mfma_f32_16x16x32_bf16(pa, vb, accv[df], 0, 0, 0);
            }
        }
        __syncthreads();   // before next tile's staging overwrites Ks/Vt/Ps
    }

    const long long obase = (long long)((v * FRAMES + f) * S_DIM + s0) * C_DIM + h * D_DIM;
    float inv[4];
    #pragma unroll
    for (int r = 0; r < 4; ++r) inv[r] = 1.0f / l_run[r];
    #pragma unroll
    for (int df = 0; df < 5; ++df)
        #pragma unroll
        for (int r = 0; r < 4; ++r)
            Ob[obase + (long long)(16 * w + 4 * g + r) * C_DIM + 16 * df + li] =
                f2bf(accv[df][r] * inv[r]);
}

// ---------------------------------------------------------------------------
// Workspace (bytes, bf16 buffers):
//   hsbf 41.9MB | Wtq/Wtk/Wtv/Wto 4x0.82MB | Qbf 41.9MB | Kbf 2.6MB |
//   Vbf 2.6MB | Obf 41.9MB   -> ~134MB total
// ---------------------------------------------------------------------------
extern "C" void kernel_launch(void* const* d_in, const int* in_sizes, int n_in,
                              void* d_out, int out_size, void* d_ws, size_t ws_size,
                              hipStream_t stream) {
    const float* hs = (const float*)d_in[0];
    const float* Wq = (const float*)d_in[1];
    const float* Wk = (const float*)d_in[2];
    const float* Wv = (const float*)d_in[3];
    const float* Wo = (const float*)d_in[4];
    const float* bq = (const float*)d_in[5];
    const float* bk = (const float*)d_in[6];
    const float* bv = (const float*)d_in[7];
    const float* bo = (const float*)d_in[8];
    float* out = (float*)d_out;

    ushort_t* ws = (ushort_t*)d_ws;
    ushort_t* hsbf = ws;                            // 32768*640
    ushort_t* Wtq  = hsbf + 32768LL * 640;          // 640*640 each
    ushort_t* Wtk  = Wtq + 640LL * 640;
    ushort_t* Wtv  = Wtk + 640LL * 640;
    ushort_t* Wto  = Wtv + 640LL * 640;
    ushort_t* Qbf  = Wto + 640LL * 640;             // 32768*640
    ushort_t* Kbf  = Qbf + 32768LL * 640;           // 2048*640
    ushort_t* Vbf  = Kbf + 2048LL * 640;            // 2048*640
    ushort_t* Obf  = Vbf + 2048LL * 640;            // 32768*640

    dim3 blk(256);
    const float scale = 0.11180339887498948f;       // 1/sqrt(80)
    const long long hs_gs = 16LL * S_DIM * C_DIM;   // frame-gather group stride (elems)

    conv_bf16<<<10240, blk, 0, stream>>>(hs, hsbf, 32768 * 640 / 8);
    transpose_w<<<dim3(10, 10), blk, 0, stream>>>(Wq, Wtq);
    transpose_w<<<dim3(10, 10), blk, 0, stream>>>(Wk, Wtk);
    transpose_w<<<dim3(10, 10), blk, 0, stream>>>(Wv, Wtv);
    transpose_w<<<dim3(10, 10), blk, 0, stream>>>(Wo, Wto);

    // Q = (hs@Wq + bq)*scale -> bf16 [32768,640]
    gemm_bf16<<<(32768 / 128) * 5, blk, 0, stream>>>(
        hsbf, Wtq, bq, nullptr, Qbf, 1, scale, 5, 15, 0LL);
    // K/V from frame-0 rows -> bf16 [2048,640] (input row = (row>>10)*hs_gs + (row&1023))
    gemm_bf16<<<(2048 / 128) * 5, blk, 0, stream>>>(
        hsbf, Wtk, bk, nullptr, Kbf, 1, 1.0f, 5, 10, hs_gs);
    gemm_bf16<<<(2048 / 128) * 5, blk, 0, stream>>>(
        hsbf, Wtv, bv, nullptr, Vbf, 1, 1.0f, 5, 10, hs_gs);

    attn_mfma<<<2 * H_NUM * FRAMES * (S_DIM / 64), blk, 0, stream>>>(Qbf, Kbf, Vbf, Obf);

    // out = Obf@Wo + bo + hs (fp32)
    gemm_bf16<<<(32768 / 128) * 5, blk, 0, stream>>>(
        Obf, Wto, bo, hs, out, 0, 1.0f, 5, 15, 0LL);
}

// Round 3
// 705.876 us; speedup vs baseline: 4.2570x; 1.1334x over previous
//
#include <hip/hip_runtime.h>
#include <math.h>

// B=32, S=1024, C=640, H=8, D=80, frames=16, videos=2
#define C_DIM 640
#define S_DIM 1024
#define H_NUM 8
#define D_DIM 80
#define FRAMES 16

typedef __attribute__((ext_vector_type(8))) short short8;   // 8 x bf16
typedef __attribute__((ext_vector_type(4))) short short4v;  // 4 x bf16
typedef __attribute__((ext_vector_type(4))) float f32x4;
typedef unsigned short ushort_t;

__device__ __forceinline__ ushort_t f2bf(float x) {
    union { float f; unsigned u; } uf; uf.f = x;
    unsigned r = uf.u + 0x7fffu + ((uf.u >> 16) & 1u);   // RNE
    return (ushort_t)(r >> 16);
}

// ---------------------------------------------------------------------------
// fp32 -> bf16 elementwise (8 elems/thread)
// ---------------------------------------------------------------------------
__global__ __launch_bounds__(256)
void conv_bf16(const float* __restrict__ in, ushort_t* __restrict__ out, int n8) {
    int i = blockIdx.x * 256 + threadIdx.x;
    if (i >= n8) return;
    const float4* p = (const float4*)(in + (long long)i * 8);
    float4 a = p[0], b = p[1];
    short8 o;
    o[0] = (short)f2bf(a.x); o[1] = (short)f2bf(a.y);
    o[2] = (short)f2bf(a.z); o[3] = (short)f2bf(a.w);
    o[4] = (short)f2bf(b.x); o[5] = (short)f2bf(b.y);
    o[6] = (short)f2bf(b.z); o[7] = (short)f2bf(b.w);
    *(short8*)(out + (long long)i * 8) = o;
}

// ---------------------------------------------------------------------------
// W [640][640] fp32 -> Wt [640][640] bf16 transposed (Wt[n][k] = W[k][n])
// ---------------------------------------------------------------------------
__global__ __launch_bounds__(256)
void transpose_w(const float* __restrict__ W, ushort_t* __restrict__ T) {
    __shared__ float Ls[64][65];
    const int tid = threadIdx.x;
    const int r0 = blockIdx.y * 64, c0 = blockIdx.x * 64;
    for (int e = tid; e < 4096; e += 256) {
        int r = e >> 6, c = e & 63;
        Ls[c][r] = W[(long long)(r0 + r) * C_DIM + c0 + c];
    }
    __syncthreads();
    for (int e = tid; e < 4096; e += 256) {
        int cc = e >> 6, rr = e & 63;
        T[(long long)(c0 + cc) * C_DIM + r0 + rr] = f2bf(Ls[cc][rr]);
    }
}

// ---------------------------------------------------------------------------
// bf16 MFMA GEMM: acc = sum_k A[row][k]*Wt[col][k]; out = (acc+bias)*scale
// out_mode: 0 = fp32 (+residual), 1 = bf16, 2 = bf16 transposed into
//           VT[v][h][dd][t] (v=row>>10, t=row&1023, h=col/80, dd=col%80)
// Tile 128x128, BK=32, 4 waves. A-row gather via rpg_shift/a_gs.
// ---------------------------------------------------------------------------
__global__ __launch_bounds__(256)
void gemm_bf16(const ushort_t* __restrict__ A, const ushort_t* __restrict__ Wt,
               const float* __restrict__ bias, const float* __restrict__ residual,
               void* __restrict__ outp, int out_mode, float out_scale,
               int nTilesN, int rpg_shift, long long a_gs)
{
    __shared__ ushort_t As[128 * 40];
    __shared__ ushort_t Bs[128 * 40];

    const int tid = threadIdx.x, bid = blockIdx.x;
    const int bm = bid / nTilesN, bn = bid % nTilesN;
    const int m0 = bm * 128, n0 = bn * 128;
    const int w = tid >> 6, l = tid & 63, g = l >> 4, li = l & 15;

    const int r0c = tid >> 2, cc = (tid & 3) * 8;
    const int maskR = (1 << rpg_shift) - 1;
    const int rowA0 = m0 + r0c, rowA1 = rowA0 + 64;
    const ushort_t* aP0 = A + (long long)(rowA0 >> rpg_shift) * a_gs
                            + (long long)(rowA0 & maskR) * C_DIM + cc;
    const ushort_t* aP1 = A + (long long)(rowA1 >> rpg_shift) * a_gs
                            + (long long)(rowA1 & maskR) * C_DIM + cc;
    const ushort_t* bP0 = Wt + (long long)(n0 + r0c) * C_DIM + cc;
    const ushort_t* bP1 = bP0 + 64 * C_DIM;
    const int sIdx0 = r0c * 40 + cc, sIdx1 = sIdx0 + 64 * 40;

    f32x4 acc[2][8] = {};

    for (int k0 = 0; k0 < C_DIM; k0 += 32) {
        __syncthreads();
        *(short8*)&As[sIdx0] = *(const short8*)(aP0 + k0);
        *(short8*)&As[sIdx1] = *(const short8*)(aP1 + k0);
        *(short8*)&Bs[sIdx0] = *(const short8*)(bP0 + k0);
        *(short8*)&Bs[sIdx1] = *(const short8*)(bP1 + k0);
        __syncthreads();
        short8 av0 = *(const short8*)&As[(32 * w + li) * 40 + 8 * g];
        short8 av1 = *(const short8*)&As[(32 * w + 16 + li) * 40 + 8 * g];
        #pragma unroll
        for (int cf = 0; cf < 8; ++cf) {
            short8 bv = *(const short8*)&Bs[(16 * cf + li) * 40 + 8 * g];
            acc[0][cf] = __builtin_amdgcn_mfma_f32_16x16x32_bf16(av0, bv, acc[0][cf], 0, 0, 0);
            acc[1][cf] = __builtin_amdgcn_mfma_f32_16x16x32_bf16(av1, bv, acc[1][cf], 0, 0, 0);
        }
    }

    #pragma unroll
    for (int fr = 0; fr < 2; ++fr) {
        #pragma unroll
        for (int cf = 0; cf < 8; ++cf) {
            const int col = n0 + 16 * cf + li;
            const float bcol = bias[col];
            if (out_mode == 2) {
                const int h = col / 80, dd = col - h * 80;
                const int row0 = m0 + 32 * w + 16 * fr + 4 * g;
                const int vv = row0 >> 10, t0 = row0 & 1023;
                short4v o;
                #pragma unroll
                for (int r = 0; r < 4; ++r)
                    o[r] = (short)f2bf(acc[fr][cf][r] + bcol);
                *(short4v*)((ushort_t*)outp +
                    ((long long)(vv * 8 + h) * 80 + dd) * 1024 + t0) = o;
            } else {
                #pragma unroll
                for (int r = 0; r < 4; ++r) {
                    const int row = m0 + 32 * w + 16 * fr + 4 * g + r;
                    float vv = (acc[fr][cf][r] + bcol) * out_scale;
                    if (residual) vv += residual[(long long)row * C_DIM + col];
                    if (out_mode == 1)
                        ((ushort_t*)outp)[(long long)row * C_DIM + col] = f2bf(vv);
                    else
                        ((float*)outp)[(long long)row * C_DIM + col] = vv;
                }
            }
        }
    }
}

// ---------------------------------------------------------------------------
// MFMA flash attention, conflict-free LDS layouts.
// Block = (v,f,h, 64 q-rows); 4 waves, wave w owns rows 16w..16w+15.
// Qs/Ks: [row][d] pitch 80 (row stride 160B = 40 dwords ≡ 8 mod 32: frag reads
//   give bank-group (2li+g)%8 -> balanced).
// Vt: [d][t] 64-wide rows, byte-XOR swizzle ((d&7)<<4): staged with b128
//   writes from pre-transposed global VT; reads/writes both 8-lanes-per-
//   4-bank-group = conflict-free.
// Ps: [q][t] pitch 72, col ^= 8*bit3(q): b16 writes land on disjoint bank
//   ranges per g (2-way dword share only); b128 reads balanced.
// Softmax in exp2 domain (log2e folded into Q scale).
// ---------------------------------------------------------------------------
__global__ __launch_bounds__(256)
void attn_mfma(const ushort_t* __restrict__ Qb, const ushort_t* __restrict__ Kb,
               const ushort_t* __restrict__ VTb, ushort_t* __restrict__ Ob)
{
    __shared__ ushort_t Qs[64 * 80];
    __shared__ ushort_t Ks[64 * 80];
    __shared__ ushort_t Vt[80 * 64];
    __shared__ ushort_t Ps[64 * 72];

    const int tid = threadIdx.x, bid = blockIdx.x;
    const int sb = bid & 15, f = (bid >> 4) & 15, h = (bid >> 8) & 7, v = bid >> 11;
    const int s0 = sb * 64;
    const int w = tid >> 6, l = tid & 63, g = l >> 4, li = l & 15;

    const ushort_t* Qg = Qb + (long long)((v * FRAMES + f) * S_DIM + s0) * C_DIM + h * D_DIM;
    const ushort_t* Kg = Kb + (long long)v * S_DIM * C_DIM + h * D_DIM;
    const ushort_t* VTg = VTb + (long long)(v * H_NUM + h) * D_DIM * S_DIM;

    for (int e = tid; e < 640; e += 256) {           // 64 rows x 10 chunks
        int t = e / 10, c = e - 10 * t;
        *(short8*)&Qs[t * 80 + c * 8] = *(const short8*)(Qg + t * C_DIM + c * 8);
    }

    float m_run[4], l_run[4];
    #pragma unroll
    for (int r = 0; r < 4; ++r) { m_run[r] = -1e30f; l_run[r] = 0.f; }
    f32x4 accv[5] = {};
    __syncthreads();

    for (int t0 = 0; t0 < S_DIM; t0 += 64) {
        for (int e = tid; e < 640; e += 256) {       // K rows
            int t = e / 10, c = e - 10 * t;
            *(short8*)&Ks[t * 80 + c * 8] = *(const short8*)(Kg + (t0 + t) * C_DIM + c * 8);
        }
        for (int e = tid; e < 640; e += 256) {       // V^T rows (d-major)
            int d = e >> 3, c = e & 7;
            short8 vv = *(const short8*)(VTg + (long long)d * S_DIM + t0 + 8 * c);
            *(short8*)&Vt[(d * 64 + 8 * c) ^ ((d & 7) << 3)] = vv;
        }
        __syncthreads();

        // ---- scores: S[q][t], q = 16w+4g+r, t = 16tf+li (log2-domain) ----
        f32x4 sc[4] = {};
        #pragma unroll
        for (int ks = 0; ks < 3; ++ks) {
            const bool valid = (ks < 2) || (g < 2);
            short8 aq = {};
            if (valid) aq = *(const short8*)&Qs[(16 * w + li) * 80 + ks * 32 + 8 * g];
            #pragma unroll
            for (int tf = 0; tf < 4; ++tf) {
                short8 bk = {};
                if (valid) bk = *(const short8*)&Ks[(16 * tf + li) * 80 + ks * 32 + 8 * g];
                sc[tf] = __builtin_amdgcn_mfma_f32_16x16x32_bf16(aq, bk, sc[tf], 0, 0, 0);
            }
        }

        // ---- online softmax (base-2) ----
        float mt[4];
        #pragma unroll
        for (int r = 0; r < 4; ++r)
            mt[r] = fmaxf(fmaxf(sc[0][r], sc[1][r]), fmaxf(sc[2][r], sc[3][r]));
        #pragma unroll
        for (int mk = 1; mk < 16; mk <<= 1)
            #pragma unroll
            for (int r = 0; r < 4; ++r)
                mt[r] = fmaxf(mt[r], __shfl_xor(mt[r], mk, 64));
        float sca[4];
        #pragma unroll
        for (int r = 0; r < 4; ++r) {
            float mn = fmaxf(m_run[r], mt[r]);
            sca[r] = exp2f(m_run[r] - mn);
            m_run[r] = mn;
        }
        float ps[4] = {0.f, 0.f, 0.f, 0.f};
        const int qswz = (g >> 1) << 3;              // 8*bit3(q)
        #pragma unroll
        for (int tf = 0; tf < 4; ++tf) {
            #pragma unroll
            for (int r = 0; r < 4; ++r) {
                float p = exp2f(sc[tf][r] - m_run[r]);
                ps[r] += p;
                const int q = 16 * w + 4 * g + r;
                Ps[q * 72 + ((16 * tf + li) ^ qswz)] = f2bf(p);
            }
        }
        #pragma unroll
        for (int mk = 1; mk < 16; mk <<= 1)
            #pragma unroll
            for (int r = 0; r < 4; ++r)
                ps[r] += __shfl_xor(ps[r], mk, 64);
        #pragma unroll
        for (int r = 0; r < 4; ++r) l_run[r] = l_run[r] * sca[r] + ps[r];
        #pragma unroll
        for (int df = 0; df < 5; ++df)
            #pragma unroll
            for (int r = 0; r < 4; ++r) accv[df][r] *= sca[r];

        __syncthreads();   // Ps visible

        // ---- PV: out[q][d] += P[q][t] V[t][d] ----
        const int rswz = ((li >> 3) & 1) << 3;       // 8*bit3(q), q=16w+li
        #pragma unroll
        for (int ks = 0; ks < 2; ++ks) {
            short8 pa = *(const short8*)&Ps[(16 * w + li) * 72 + ((32 * ks + 8 * g) ^ rswz)];
            #pragma unroll
            for (int df = 0; df < 5; ++df) {
                short8 vb = *(const short8*)&Vt[((16 * df + li) * 64 + 32 * ks + 8 * g) ^ ((li & 7) << 3)];
                accv[df] = __builtin_amdgcn_mfma_f32_16x16x32_bf16(pa, vb, accv[df], 0, 0, 0);
            }
        }
        __syncthreads();   // before next tile's staging overwrites Ks/Vt/Ps
    }

    const long long obase = (long long)((v * FRAMES + f) * S_DIM + s0) * C_DIM + h * D_DIM;
    float inv[4];
    #pragma unroll
    for (int r = 0; r < 4; ++r) inv[r] = 1.0f / l_run[r];
    #pragma unroll
    for (int df = 0; df < 5; ++df)
        #pragma unroll
        for (int r = 0; r < 4; ++r)
            Ob[obase + (long long)(16 * w + 4 * g + r) * C_DIM + 16 * df + li] =
                f2bf(accv[df][r] * inv[r]);
}

// ---------------------------------------------------------------------------
extern "C" void kernel_launch(void* const* d_in, const int* in_sizes, int n_in,
                              void* d_out, int out_size, void* d_ws, size_t ws_size,
                              hipStream_t stream) {
    const float* hs = (const float*)d_in[0];
    const float* Wq = (const float*)d_in[1];
    const float* Wk = (const float*)d_in[2];
    const float* Wv = (const float*)d_in[3];
    const float* Wo = (const float*)d_in[4];
    const float* bq = (const float*)d_in[5];
    const float* bk = (const float*)d_in[6];
    const float* bv = (const float*)d_in[7];
    const float* bo = (const float*)d_in[8];
    float* out = (float*)d_out;

    ushort_t* ws = (ushort_t*)d_ws;
    ushort_t* hsbf = ws;                            // 32768*640
    ushort_t* Wtq  = hsbf + 32768LL * 640;          // 640*640 each
    ushort_t* Wtk  = Wtq + 640LL * 640;
    ushort_t* Wtv  = Wtk + 640LL * 640;
    ushort_t* Wto  = Wtv + 640LL * 640;
    ushort_t* Qbf  = Wto + 640LL * 640;             // 32768*640
    ushort_t* Kbf  = Qbf + 32768LL * 640;           // 2048*640
    ushort_t* VTbf = Kbf + 2048LL * 640;            // 2*8*80*1024
    ushort_t* Obf  = VTbf + 2LL * 8 * 80 * 1024;    // 32768*640

    dim3 blk(256);
    // 1/sqrt(80) * log2(e): softmax runs in exp2 domain
    const float scale = 0.11180339887498948f * 1.4426950408889634f;
    const long long hs_gs = 16LL * S_DIM * C_DIM;   // frame-gather group stride

    conv_bf16<<<10240, blk, 0, stream>>>(hs, hsbf, 32768 * 640 / 8);
    transpose_w<<<dim3(10, 10), blk, 0, stream>>>(Wq, Wtq);
    transpose_w<<<dim3(10, 10), blk, 0, stream>>>(Wk, Wtk);
    transpose_w<<<dim3(10, 10), blk, 0, stream>>>(Wv, Wtv);
    transpose_w<<<dim3(10, 10), blk, 0, stream>>>(Wo, Wto);

    // Q = (hs@Wq + bq)*scale -> bf16 [32768,640]
    gemm_bf16<<<(32768 / 128) * 5, blk, 0, stream>>>(
        hsbf, Wtq, bq, nullptr, Qbf, 1, scale, 5, 15, 0LL);
    // K from frame-0 rows -> bf16 [2048,640]
    gemm_bf16<<<(2048 / 128) * 5, blk, 0, stream>>>(
        hsbf, Wtk, bk, nullptr, Kbf, 1, 1.0f, 5, 10, hs_gs);
    // V from frame-0 rows -> transposed VT[v][h][80][1024]
    gemm_bf16<<<(2048 / 128) * 5, blk, 0, stream>>>(
        hsbf, Wtv, bv, nullptr, VTbf, 2, 1.0f, 5, 10, hs_gs);

    attn_mfma<<<2 * H_NUM * FRAMES * (S_DIM / 64), blk, 0, stream>>>(Qbf, Kbf, VTbf, Obf);

    // out = Obf@Wo + bo + hs (fp32)
    gemm_bf16<<<(32768 / 128) * 5, blk, 0, stream>>>(
        Obf, Wto, bo, hs, out, 0, 1.0f, 5, 15, 0LL);
}